// Round 2
// baseline (3390.862 us; speedup 1.0000x reference)
//
#include <hip/hip_runtime.h>
#include <math.h>

#define B_TOT 131072
#define NOBS 17
#define NACT 6
#define NM 8
#define HID 256
#define TS 64      // samples per block (lane = sample)
#define NT 512     // threads per block = 8 waves
#define CPW 32     // columns per wave = HID / 8

// fast fp32 tanh for the tolerance-insensitive value path (abs err ~1e-6)
__device__ __forceinline__ float tanh_fast(float x) {
  float ax = fminf(fabsf(x), 15.0f);
  float e = __expf(2.0f * ax);
  float t = 1.0f - 2.0f / (e + 1.0f);
  return copysignf(t, x);
}

extern "C" __global__ __launch_bounds__(NT, 2)
void ppo_fused(const float* __restrict__ obs,
               const float* __restrict__ eW1, const float* __restrict__ eb1,
               const float* __restrict__ eW2, const float* __restrict__ eb2,
               const float* __restrict__ muW, const float* __restrict__ mub,
               const float* __restrict__ logstd,
               const float* __restrict__ vW1, const float* __restrict__ vb1,
               const float* __restrict__ vW2, const float* __restrict__ vb2,
               const float* __restrict__ vW3, const float* __restrict__ vb3,
               const float* __restrict__ cen, const float* __restrict__ smean,
               const float* __restrict__ svar,
               float* __restrict__ out)
{
  // fp64 activations: routing argmin must match a high-precision reference.
  __shared__ double act[HID * TS];         // 128 KB: h -> feat -> v1 -> v2, [k][sample]
  __shared__ double scbuf[NM * TS];        // 4 KB: routing d^2 (fp64)
  __shared__ double zsbuf[HID];            // 2 KB: 1/sqrt(var+1e-6)
  __shared__ float  mubuf[NM * TS * NACT]; // 12 KB: mu for all charts (aliased: obs staging)

  const int tid  = threadIdx.x;
  const int lane = tid & 63;
  const int wid  = tid >> 6;
  const int c0   = wid * CPW;
  const int s0   = blockIdx.x * TS;
  float* obs_s = mubuf;  // [NOBS][TS] staging alias (dead before mubuf is written)

  // ---- stage obs (coalesced), whitening scale in fp64
  for (int idx = tid; idx < TS * NOBS; idx += NT) {
    int s = idx / NOBS, i = idx - s * NOBS;
    obs_s[i * TS + s] = obs[s0 * NOBS + idx];
  }
  if (tid < HID) zsbuf[tid] = 1.0 / sqrt((double)svar[tid] + 1e-6);
  __syncthreads();

  // ---- encoder layer 1 (fp64): h = tanh(obs @ W1 + b1)
  {
    double acc[CPW];
#pragma unroll
    for (int c = 0; c < CPW; ++c) acc[c] = (double)eb1[c0 + c];
    double ob[NOBS];
#pragma unroll
    for (int i = 0; i < NOBS; ++i) ob[i] = (double)obs_s[i * TS + lane];
#pragma unroll
    for (int i = 0; i < NOBS; ++i) {
      const float* w = &eW1[i * HID + c0];
#pragma unroll
      for (int c = 0; c < CPW; ++c) acc[c] = fma(ob[i], (double)w[c], acc[c]);
    }
#pragma unroll
    for (int c = 0; c < CPW; ++c) act[(c0 + c) * TS + lane] = tanh(acc[c]);
  }
  __syncthreads();  // h ready

  // ---- encoder layer 2 (fp64): feat = tanh(h @ W2 + b2)
  {
    double acc[CPW];
#pragma unroll
    for (int c = 0; c < CPW; ++c) acc[c] = (double)eb2[c0 + c];
#pragma unroll 2
    for (int k = 0; k < HID; ++k) {
      double a = act[k * TS + lane];
      const float* w = &eW2[k * HID + c0];
#pragma unroll
      for (int c = 0; c < CPW; ++c) acc[c] = fma(a, (double)w[c], acc[c]);
    }
    __syncthreads();  // all h reads done before overwrite
#pragma unroll
    for (int c = 0; c < CPW; ++c) act[(c0 + c) * TS + lane] = tanh(acc[c]);
  }
  __syncthreads();  // feat ready

  // ---- routing d^2 (fp64) + mu head (fp32) for chart m = wid
  {
    double dot = 0.0, zn = 0.0, cn = 0.0;
    float mu[NACT];
#pragma unroll
    for (int a = 0; a < NACT; ++a) mu[a] = mub[wid * NACT + a];
#pragma unroll 2
    for (int k = 0; k < HID; ++k) {
      double f  = act[k * TS + lane];
      double zw = (f - (double)smean[k]) * zsbuf[k];
      double ck = (double)cen[wid * HID + k];
      dot = fma(zw, ck, dot);
      zn  = fma(zw, zw, zn);
      cn  = fma(ck, ck, cn);
      float ff = (float)f;
      const float* w = &muW[(wid * HID + k) * NACT];
#pragma unroll
      for (int a = 0; a < NACT; ++a) mu[a] = fmaf(ff, w[a], mu[a]);
    }
    scbuf[wid * TS + lane] = zn - 2.0 * dot + cn;  // matches ref formula
#pragma unroll
    for (int a = 0; a < NACT; ++a) mubuf[(wid * TS + lane) * NACT + a] = mu[a];
  }

  // ---- value layer 1 (fp32 math, fp64 storage slot)
  {
    float acc[CPW];
#pragma unroll
    for (int c = 0; c < CPW; ++c) acc[c] = vb1[c0 + c];
#pragma unroll 4
    for (int k = 0; k < HID; ++k) {
      float f = (float)act[k * TS + lane];
      const float* w = &vW1[k * HID + c0];
#pragma unroll
      for (int c = 0; c < CPW; ++c) acc[c] = fmaf(f, w[c], acc[c]);
    }
    __syncthreads();  // feat reads (routing + mu + val1) all done
#pragma unroll
    for (int c = 0; c < CPW; ++c) act[(c0 + c) * TS + lane] = (double)tanh_fast(acc[c]);
  }
  __syncthreads();  // v1 ready

  // ---- value layer 2
  {
    float acc[CPW];
#pragma unroll
    for (int c = 0; c < CPW; ++c) acc[c] = vb2[c0 + c];
#pragma unroll 4
    for (int k = 0; k < HID; ++k) {
      float f = (float)act[k * TS + lane];
      const float* w = &vW2[k * HID + c0];
#pragma unroll
      for (int c = 0; c < CPW; ++c) acc[c] = fmaf(f, w[c], acc[c]);
    }
    __syncthreads();
#pragma unroll
    for (int c = 0; c < CPW; ++c) act[(c0 + c) * TS + lane] = (double)tanh_fast(acc[c]);
  }
  __syncthreads();  // v2 ready

  // ---- argmin routing, value dot, output (wave 0; lane = sample)
  if (wid == 0) {
    int best = 0;
    double bs = scbuf[lane];
#pragma unroll
    for (int m = 1; m < NM; ++m) {
      double sm = scbuf[m * TS + lane];
      if (sm < bs) { bs = sm; best = m; }  // strict < : lowest index on tie
    }
    float v = vb3[0];
#pragma unroll 4
    for (int k = 0; k < HID; ++k) v = fmaf((float)act[k * TS + lane], vW3[k], v);
    float* orow = &out[(size_t)(s0 + lane) * (2 * NACT + 1)];
#pragma unroll
    for (int a = 0; a < NACT; ++a) orow[a] = mubuf[(best * TS + lane) * NACT + a];
#pragma unroll
    for (int a = 0; a < NACT; ++a) {
      float ls = logstd[best * NACT + a];
      orow[NACT + a] = fminf(fmaxf(ls, -20.0f), 2.0f);
    }
    orow[2 * NACT] = v;
  }
}

extern "C" void kernel_launch(void* const* d_in, const int* in_sizes, int n_in,
                              void* d_out, int out_size, void* d_ws, size_t ws_size,
                              hipStream_t stream) {
  const float* obs   = (const float*)d_in[0];
  const float* eW1   = (const float*)d_in[1];
  const float* eb1   = (const float*)d_in[2];
  const float* eW2   = (const float*)d_in[3];
  const float* eb2   = (const float*)d_in[4];
  const float* muW   = (const float*)d_in[5];
  const float* mub   = (const float*)d_in[6];
  const float* lstd  = (const float*)d_in[7];
  const float* vW1   = (const float*)d_in[8];
  const float* vb1   = (const float*)d_in[9];
  const float* vW2   = (const float*)d_in[10];
  const float* vb2   = (const float*)d_in[11];
  const float* vW3   = (const float*)d_in[12];
  const float* vb3   = (const float*)d_in[13];
  const float* cen   = (const float*)d_in[14];
  const float* smean = (const float*)d_in[15];
  const float* svar  = (const float*)d_in[16];
  float* out = (float*)d_out;

  dim3 grid(B_TOT / TS);
  dim3 block(NT);
  hipLaunchKernelGGL(ppo_fused, grid, block, 0, stream,
                     obs, eW1, eb1, eW2, eb2, muW, mub, lstd,
                     vW1, vb1, vW2, vb2, vW3, vb3, cen, smean, svar, out);
}

// Round 3
// 3029.597 us; speedup vs baseline: 1.1192x; 1.1192x over previous
//
#include <hip/hip_runtime.h>
#include <math.h>

#define B_TOT 131072
#define NOBS 17
#define NACT 6
#define NM 8
#define HID 256
#define TS 64      // samples per block (lane = sample)
#define NT 512     // threads per block = 8 waves
#define CPW 32     // columns per wave = HID / 8
#define NOUT (2 * NACT + 1)
#define EPS_MARGIN 1e-2f   // fp32 d2 worst-case error ~1e-3; 10x safety
#define CAP_MAX 65536

// fast fp32 tanh (abs err ~1e-6): fine for values; routing is protected by recheck
__device__ __forceinline__ float tanh_fast(float x) {
  float ax = fminf(fabsf(x), 15.0f);
  float e = __expf(2.0f * ax);
  float t = 1.0f - 2.0f / (e + 1.0f);
  return copysignf(t, x);
}

extern "C" __global__ void ppo_zero(int* cnt) {
  if (cnt && threadIdx.x == 0) cnt[0] = 0;
}

// ---------------- Pass A: fp32 pipeline + near-tie flagging ----------------
extern "C" __global__ __launch_bounds__(NT, 4)
void ppo_fp32(const float* __restrict__ obs,
              const float* __restrict__ eW1, const float* __restrict__ eb1,
              const float* __restrict__ eW2, const float* __restrict__ eb2,
              const float* __restrict__ muW, const float* __restrict__ mub,
              const float* __restrict__ logstd,
              const float* __restrict__ vW1, const float* __restrict__ vb1,
              const float* __restrict__ vW2, const float* __restrict__ vb2,
              const float* __restrict__ vW3, const float* __restrict__ vb3,
              const float* __restrict__ cen, const float* __restrict__ smean,
              const float* __restrict__ svar,
              float* __restrict__ out,
              int* cnt, int* flags, int cap)
{
  __shared__ float act[HID * TS];          // 64 KB: h -> feat -> v1 -> v2, [k][sample]
  __shared__ float mubuf[NM * TS * NACT];  // 12 KB: mu all charts (aliased: obs staging)
  __shared__ float scbuf[NM * TS];         // 2 KB: routing d^2
  __shared__ float zsbuf[HID];             // 1 KB: 1/sqrt(var+1e-6)  (total 80896 B)

  const int tid  = threadIdx.x;
  const int lane = tid & 63;
  const int wid  = tid >> 6;
  const int c0   = wid * CPW;
  const int s0   = blockIdx.x * TS;
  float* obs_s = mubuf;  // [NOBS][TS] staging alias (dead before mubuf written)

  for (int idx = tid; idx < TS * NOBS; idx += NT) {
    int s = idx / NOBS, i = idx - s * NOBS;
    obs_s[i * TS + s] = obs[s0 * NOBS + idx];
  }
  if (tid < HID) zsbuf[tid] = (float)(1.0 / sqrt((double)svar[tid] + 1e-6));
  __syncthreads();

  // ---- encoder layer 1: h = tanh(obs @ W1 + b1)
  {
    float acc[CPW];
#pragma unroll
    for (int c = 0; c < CPW; ++c) acc[c] = eb1[c0 + c];
    float ob[NOBS];
#pragma unroll
    for (int i = 0; i < NOBS; ++i) ob[i] = obs_s[i * TS + lane];
#pragma unroll
    for (int i = 0; i < NOBS; ++i) {
      const float* w = &eW1[i * HID + c0];
#pragma unroll
      for (int c = 0; c < CPW; ++c) acc[c] = fmaf(ob[i], w[c], acc[c]);
    }
#pragma unroll
    for (int c = 0; c < CPW; ++c) act[(c0 + c) * TS + lane] = tanh_fast(acc[c]);
  }
  __syncthreads();  // h ready

  // ---- encoder layer 2: feat = tanh(h @ W2 + b2)
  {
    float acc[CPW];
#pragma unroll
    for (int c = 0; c < CPW; ++c) acc[c] = eb2[c0 + c];
#pragma unroll 4
    for (int k = 0; k < HID; ++k) {
      float a = act[k * TS + lane];
      const float* w = &eW2[k * HID + c0];
#pragma unroll
      for (int c = 0; c < CPW; ++c) acc[c] = fmaf(a, w[c], acc[c]);
    }
    __syncthreads();  // all h reads done before overwrite
#pragma unroll
    for (int c = 0; c < CPW; ++c) act[(c0 + c) * TS + lane] = tanh_fast(acc[c]);
  }
  __syncthreads();  // feat ready

  // ---- routing d^2 (fp64 accumulation from fp32 feat) + mu head, chart = wid
  {
    double dot = 0.0, zn = 0.0, cn = 0.0;
    float mu[NACT];
#pragma unroll
    for (int a = 0; a < NACT; ++a) mu[a] = mub[wid * NACT + a];
#pragma unroll 2
    for (int k = 0; k < HID; ++k) {
      float f  = act[k * TS + lane];
      double zw = ((double)f - (double)smean[k]) * (double)zsbuf[k];
      double ck = (double)cen[wid * HID + k];
      dot = fma(zw, ck, dot);
      zn  = fma(zw, zw, zn);
      cn  = fma(ck, ck, cn);
      const float* w = &muW[(wid * HID + k) * NACT];
#pragma unroll
      for (int a = 0; a < NACT; ++a) mu[a] = fmaf(f, w[a], mu[a]);
    }
    scbuf[wid * TS + lane] = (float)(zn - 2.0 * dot + cn);
#pragma unroll
    for (int a = 0; a < NACT; ++a) mubuf[(wid * TS + lane) * NACT + a] = mu[a];
  }

  // ---- value layer 1 (reads feat)
  {
    float acc[CPW];
#pragma unroll
    for (int c = 0; c < CPW; ++c) acc[c] = vb1[c0 + c];
#pragma unroll 4
    for (int k = 0; k < HID; ++k) {
      float f = act[k * TS + lane];
      const float* w = &vW1[k * HID + c0];
#pragma unroll
      for (int c = 0; c < CPW; ++c) acc[c] = fmaf(f, w[c], acc[c]);
    }
    __syncthreads();  // feat reads (routing + mu + val1) all done
#pragma unroll
    for (int c = 0; c < CPW; ++c) act[(c0 + c) * TS + lane] = tanh_fast(acc[c]);
  }
  __syncthreads();  // v1 ready

  // ---- value layer 2
  {
    float acc[CPW];
#pragma unroll
    for (int c = 0; c < CPW; ++c) acc[c] = vb2[c0 + c];
#pragma unroll 4
    for (int k = 0; k < HID; ++k) {
      float f = act[k * TS + lane];
      const float* w = &vW2[k * HID + c0];
#pragma unroll
      for (int c = 0; c < CPW; ++c) acc[c] = fmaf(f, w[c], acc[c]);
    }
    __syncthreads();
#pragma unroll
    for (int c = 0; c < CPW; ++c) act[(c0 + c) * TS + lane] = tanh_fast(acc[c]);
  }
  __syncthreads();  // v2 ready

  // ---- argmin + margin flag + value dot + output (wave 0; lane = sample)
  if (wid == 0) {
    int best = 0;
    float bs = scbuf[lane];
    float bs2 = 3.4e38f;
#pragma unroll
    for (int m = 1; m < NM; ++m) {
      float sm = scbuf[m * TS + lane];
      if (sm < bs) { bs2 = bs; bs = sm; best = m; }  // strict <
      else if (sm < bs2) bs2 = sm;
    }
    if (cnt && (bs2 - bs) < EPS_MARGIN) {
      int idx = atomicAdd(cnt, 1);
      if (idx < cap) flags[idx] = s0 + lane;
    }
    float v = vb3[0];
#pragma unroll 4
    for (int k = 0; k < HID; ++k) v = fmaf(act[k * TS + lane], vW3[k], v);
    float* orow = &out[(size_t)(s0 + lane) * NOUT];
#pragma unroll
    for (int a = 0; a < NACT; ++a) orow[a] = mubuf[(best * TS + lane) * NACT + a];
#pragma unroll
    for (int a = 0; a < NACT; ++a) {
      float ls = logstd[best * NACT + a];
      orow[NACT + a] = fminf(fmaxf(ls, -20.0f), 2.0f);
    }
    orow[2 * NACT] = v;
  }
}

// ---------------- Pass B: fp64 recheck of flagged samples ----------------
extern "C" __global__ __launch_bounds__(256, 2)
void ppo_recheck(const float* __restrict__ obs,
                 const float* __restrict__ eW1, const float* __restrict__ eb1,
                 const float* __restrict__ eW2, const float* __restrict__ eb2,
                 const float* __restrict__ muW, const float* __restrict__ mub,
                 const float* __restrict__ logstd,
                 const float* __restrict__ cen, const float* __restrict__ smean,
                 const float* __restrict__ svar,
                 float* __restrict__ out,
                 const int* cnt, const int* flags, int cap)
{
  if (!cnt) return;
  __shared__ double hbuf[HID];
  __shared__ double fbuf[HID];
  __shared__ double d2buf[NM];
  __shared__ double obsd[NOBS];
  __shared__ int bestv;
  const int tid = threadIdx.x;
  const int n = min(cnt[0], cap);

  for (int i = blockIdx.x; i < n; i += gridDim.x) {
    const int s = flags[i];
    if (tid < NOBS) obsd[tid] = (double)obs[(size_t)s * NOBS + tid];
    __syncthreads();
    // enc1, column = tid (fp64, exact replica of verified round-2 math)
    double a1 = (double)eb1[tid];
    for (int k = 0; k < NOBS; ++k) a1 = fma(obsd[k], (double)eW1[k * HID + tid], a1);
    hbuf[tid] = tanh(a1);
    __syncthreads();
    double a2 = (double)eb2[tid];
    for (int k = 0; k < HID; ++k) a2 = fma(hbuf[k], (double)eW2[k * HID + tid], a2);
    fbuf[tid] = tanh(a2);
    __syncthreads();
    // d^2 per chart g = tid>>5, 32 lanes per chart
    {
      int g = tid >> 5, l = tid & 31;
      double dot = 0.0, zn = 0.0, cn = 0.0;
      for (int j = 0; j < HID / 32; ++j) {
        int k = l + j * 32;
        double zs = 1.0 / sqrt((double)svar[k] + 1e-6);
        double zw = (fbuf[k] - (double)smean[k]) * zs;
        double ck = (double)cen[g * HID + k];
        dot = fma(zw, ck, dot);
        zn  = fma(zw, zw, zn);
        cn  = fma(ck, ck, cn);
      }
      for (int m = 16; m >= 1; m >>= 1) {
        dot += __shfl_xor(dot, m, 32);
        zn  += __shfl_xor(zn,  m, 32);
        cn  += __shfl_xor(cn,  m, 32);
      }
      if (l == 0) d2buf[g] = zn - 2.0 * dot + cn;
    }
    __syncthreads();
    if (tid == 0) {
      int best = 0;
      double bs = d2buf[0];
      for (int m = 1; m < NM; ++m)
        if (d2buf[m] < bs) { bs = d2buf[m]; best = m; }  // strict <
      bestv = best;
    }
    __syncthreads();
    const int best = bestv;
    if (tid < NACT) {
      float acc = mub[best * NACT + tid];
      for (int k = 0; k < HID; ++k)
        acc = fmaf((float)fbuf[k], muW[(best * HID + k) * NACT + tid], acc);
      out[(size_t)s * NOUT + tid] = acc;
    } else if (tid < 2 * NACT) {
      int a = tid - NACT;
      float ls = logstd[best * NACT + a];
      out[(size_t)s * NOUT + NACT + a] = fminf(fmaxf(ls, -20.0f), 2.0f);
    }
    __syncthreads();  // protect obsd/hbuf/fbuf before next flagged sample
  }
}

extern "C" void kernel_launch(void* const* d_in, const int* in_sizes, int n_in,
                              void* d_out, int out_size, void* d_ws, size_t ws_size,
                              hipStream_t stream) {
  const float* obs   = (const float*)d_in[0];
  const float* eW1   = (const float*)d_in[1];
  const float* eb1   = (const float*)d_in[2];
  const float* eW2   = (const float*)d_in[3];
  const float* eb2   = (const float*)d_in[4];
  const float* muW   = (const float*)d_in[5];
  const float* mub   = (const float*)d_in[6];
  const float* lstd  = (const float*)d_in[7];
  const float* vW1   = (const float*)d_in[8];
  const float* vb1   = (const float*)d_in[9];
  const float* vW2   = (const float*)d_in[10];
  const float* vb2   = (const float*)d_in[11];
  const float* vW3   = (const float*)d_in[12];
  const float* vb3   = (const float*)d_in[13];
  const float* cen   = (const float*)d_in[14];
  const float* smean = (const float*)d_in[15];
  const float* svar  = (const float*)d_in[16];
  float* out = (float*)d_out;

  int* cnt = nullptr; int* flags = nullptr; int cap = 0;
  if (ws_size >= 1024) {
    cnt = (int*)d_ws;
    flags = cnt + 16;  // 64 B offset
    size_t c = (ws_size - 64) / 4;
    cap = (int)(c < (size_t)CAP_MAX ? c : (size_t)CAP_MAX);
  }

  hipLaunchKernelGGL(ppo_zero, dim3(1), dim3(64), 0, stream, cnt);
  hipLaunchKernelGGL(ppo_fp32, dim3(B_TOT / TS), dim3(NT), 0, stream,
                     obs, eW1, eb1, eW2, eb2, muW, mub, lstd,
                     vW1, vb1, vW2, vb2, vW3, vb3, cen, smean, svar, out,
                     cnt, flags, cap);
  hipLaunchKernelGGL(ppo_recheck, dim3(512), dim3(256), 0, stream,
                     obs, eW1, eb1, eW2, eb2, muW, mub, lstd,
                     cen, smean, svar, out, cnt, flags, cap);
}

// Round 4
// 426.499 us; speedup vs baseline: 7.9505x; 7.1034x over previous
//
#include <hip/hip_runtime.h>
#include <math.h>

typedef __attribute__((ext_vector_type(8))) short bf16x8;
typedef __attribute__((ext_vector_type(4))) float f32x4;

#define B_TOT 131072
#define NOBS 17
#define NACT 6
#define NM 8
#define HID 256
#define TS 64
#define NT 512
#define NW 8
#define NOUT 13
#define EPS_MARGIN 0.02f
#define CAPF 65536

// ---- workspace layout (bytes) ----
#define OFF_FLAGS 64
#define OFF_W2H (OFF_FLAGS + 4*CAPF)
#define SZW (HID*HID*2)
#define OFF_W2L (OFF_W2H + SZW)
#define OFF_V1H (OFF_W2L + SZW)
#define OFF_V1L (OFF_V1H + SZW)
#define OFF_V2H (OFF_V1L + SZW)
#define OFF_V2L (OFF_V2H + SZW)
#define OFF_MUH (OFF_V2L + SZW)          /* 48*256*2 */
#define OFF_MUL (OFF_MUH + 48*HID*2)
#define OFF_G   (OFF_MUL + 48*HID*2)     /* 256*8*4  */
#define OFF_G0  (OFF_G + HID*NM*4)
#define WS_NEED (OFF_G0 + 64)

__device__ __forceinline__ float tanh_fast(float x) {
  float ax = fminf(fabsf(x), 15.0f);
  float e = __expf(2.0f * ax);
  float t = 1.0f - 2.0f / (e + 1.0f);
  return copysignf(t, x);
}
__device__ __forceinline__ unsigned short f2bf(float f) {  // RNE
  unsigned int u = __float_as_uint(f);
  u = (u + 0x7fffu + ((u >> 16) & 1u)) >> 16;
  return (unsigned short)u;
}
__device__ __forceinline__ float bf2f(unsigned short h) {
  return __uint_as_float(((unsigned int)h) << 16);
}
// swizzled element index into a [TS][HID] bf16 activation buffer
__device__ __forceinline__ int aidx(int s, int k) {
  return (s << 8) + (k ^ ((s & 7) << 3));
}
__device__ __forceinline__ f32x4 MFMA(bf16x8 a, bf16x8 b, f32x4 c) {
  return __builtin_amdgcn_mfma_f32_16x16x32_bf16(a, b, c, 0, 0, 0);
}

extern "C" __global__ void ppo_zero(int* cnt) {
  if (cnt && threadIdx.x == 0) cnt[0] = 0;
}

// ---------------- prep: transpose + bf16 hi/lo split of weights, G matrix ----------------
extern "C" __global__ __launch_bounds__(256)
void ppo_prep(const float* __restrict__ eW2, const float* __restrict__ vW1,
              const float* __restrict__ vW2, const float* __restrict__ muW,
              const float* __restrict__ cen, const float* __restrict__ svar,
              unsigned char* wsb)
{
  int t = blockIdx.x * 256 + threadIdx.x;  // 0..65535
  unsigned short* W2H = (unsigned short*)(wsb + OFF_W2H);
  unsigned short* W2L = (unsigned short*)(wsb + OFF_W2L);
  unsigned short* V1H = (unsigned short*)(wsb + OFF_V1H);
  unsigned short* V1L = (unsigned short*)(wsb + OFF_V1L);
  unsigned short* V2H = (unsigned short*)(wsb + OFF_V2H);
  unsigned short* V2L = (unsigned short*)(wsb + OFF_V2L);
  unsigned short* MUH = (unsigned short*)(wsb + OFF_MUH);
  unsigned short* MUL = (unsigned short*)(wsb + OFF_MUL);
  float* G = (float*)(wsb + OFF_G);
  if (t < HID * HID) {
    int k = t >> 8, c = t & 255;
    int src = k * HID + c, dst = c * HID + k;
    float w, fh; unsigned short hi;
    w = eW2[src]; hi = f2bf(w); fh = bf2f(hi); W2H[dst] = hi; W2L[dst] = f2bf(w - fh);
    w = vW1[src]; hi = f2bf(w); fh = bf2f(hi); V1H[dst] = hi; V1L[dst] = f2bf(w - fh);
    w = vW2[src]; hi = f2bf(w); fh = bf2f(hi); V2H[dst] = hi; V2L[dst] = f2bf(w - fh);
  }
  if (t < 48 * HID) {
    int ma = t >> 8, kk = t & 255;
    int m = ma / NACT, a = ma - NACT * m;
    float w = muW[(m * HID + kk) * NACT + a];
    unsigned short hi = f2bf(w);
    MUH[ma * HID + kk] = hi; MUL[ma * HID + kk] = f2bf(w - bf2f(hi));
  }
  if (t < HID * NM) {
    int kk = t >> 3, m = t & 7;
    double s = 1.0 / sqrt((double)svar[kk] + 1e-6);
    G[kk * NM + m] = (float)(-2.0 * s * (double)cen[m * HID + kk]);
  }
}

extern "C" __global__ __launch_bounds__(NT)
void ppo_prep_g0(const float* __restrict__ cen, const float* __restrict__ smean,
                 const float* __restrict__ svar, unsigned char* wsb)
{
  int m = threadIdx.x >> 6, lane = threadIdx.x & 63;
  double acc = 0.0;
  for (int k = lane; k < HID; k += 64) {
    double s = 1.0 / sqrt((double)svar[k] + 1e-6);
    double c = (double)cen[m * HID + k];
    acc += c * (2.0 * (double)smean[k] * s + c);
  }
#pragma unroll
  for (int w = 32; w >= 1; w >>= 1) acc += __shfl_xor(acc, w);
  if (lane == 0) ((float*)(wsb + OFF_G0))[m] = (float)acc;
}

// ---------------- 3/2-pass split-bf16 MFMA tile: 64 rows x 32 cols, K=256 ----------------
template<bool ALO, bool BLO>
__device__ __forceinline__ void gemm_tile(const unsigned short* Ah, const unsigned short* Al,
                                          const unsigned short* BTh, const unsigned short* BTl,
                                          const float* __restrict__ bias,
                                          int c0, int l15, int h, f32x4 acc[4][2])
{
  float b0 = bias[c0 + l15], b1 = bias[c0 + 16 + l15];
#pragma unroll
  for (int mt = 0; mt < 4; ++mt) {
    acc[mt][0] = (f32x4){b0, b0, b0, b0};
    acc[mt][1] = (f32x4){b1, b1, b1, b1};
  }
#pragma unroll
  for (int kt = 0; kt < 8; ++kt) {
    int kb = kt * 32 + 8 * h;
    bf16x8 bh0 = *(const bf16x8*)(BTh + (c0 + l15) * HID + kb);
    bf16x8 bh1 = *(const bf16x8*)(BTh + (c0 + 16 + l15) * HID + kb);
    bf16x8 bl0, bl1;
    if (BLO) {
      bl0 = *(const bf16x8*)(BTl + (c0 + l15) * HID + kb);
      bl1 = *(const bf16x8*)(BTl + (c0 + 16 + l15) * HID + kb);
    }
    bf16x8 ah[4], al[4];
#pragma unroll
    for (int mt = 0; mt < 4; ++mt) {
      int s = 16 * mt + l15;
      ah[mt] = *(const bf16x8*)(Ah + aidx(s, kb));
      if (ALO) al[mt] = *(const bf16x8*)(Al + aidx(s, kb));
    }
#pragma unroll
    for (int mt = 0; mt < 4; ++mt) {
      acc[mt][0] = MFMA(ah[mt], bh0, acc[mt][0]);
      acc[mt][1] = MFMA(ah[mt], bh1, acc[mt][1]);
      if (ALO) { acc[mt][0] = MFMA(al[mt], bh0, acc[mt][0]);
                 acc[mt][1] = MFMA(al[mt], bh1, acc[mt][1]); }
      if (BLO) { acc[mt][0] = MFMA(ah[mt], bl0, acc[mt][0]);
                 acc[mt][1] = MFMA(ah[mt], bl1, acc[mt][1]); }
    }
  }
}

// epilogue: tanh + hi/lo split + swizzled LDS store
__device__ __forceinline__ void epi_split(f32x4 acc[4][2], unsigned short* Dh, unsigned short* Dl,
                                          int c0, int l15, int h)
{
#pragma unroll
  for (int mt = 0; mt < 4; ++mt)
#pragma unroll
    for (int nt = 0; nt < 2; ++nt) {
      int c = c0 + 16 * nt + l15;
#pragma unroll
      for (int r = 0; r < 4; ++r) {
        int s = 16 * mt + 4 * h + r;
        float f = tanh_fast(acc[mt][nt][r]);
        unsigned short hi = f2bf(f);
        int id = aidx(s, c);
        Dh[id] = hi; Dl[id] = f2bf(f - bf2f(hi));
      }
    }
}

// ---------------- main fused kernel ----------------
extern "C" __global__ __launch_bounds__(NT, 2)
void ppo_mfma(const float* __restrict__ obs,
              const float* __restrict__ eW1, const float* __restrict__ eb1,
              const float* __restrict__ eb2,
              const float* __restrict__ mub, const float* __restrict__ logstd,
              const float* __restrict__ vb1, const float* __restrict__ vb2,
              const float* __restrict__ vW3, const float* __restrict__ vb3,
              const unsigned char* __restrict__ wsb,
              float* __restrict__ out, int* cnt, int* flags, int cap)
{
  __shared__ unsigned short Ahi[TS * HID];  // 32 KB each
  __shared__ unsigned short Alo[TS * HID];
  __shared__ unsigned short Bhi[TS * HID];
  __shared__ unsigned short Blo[TS * HID];
  __shared__ float Glds[HID * NM];          // 8 KB
  __shared__ float w3lds[HID];
  __shared__ float lslds[48];
  __shared__ float sclds[NM * TS];
  __shared__ float vpart[NW * TS];
  __shared__ float mulds[48 * 65];

  const int tid  = threadIdx.x;
  const int lane = tid & 63;
  const int wid  = tid >> 6;
  const int l15  = lane & 15;
  const int h    = lane >> 4;
  const int c0   = wid * 32;
  const int s0   = blockIdx.x * TS;

  const unsigned short* W2H = (const unsigned short*)(wsb + OFF_W2H);
  const unsigned short* W2L = (const unsigned short*)(wsb + OFF_W2L);
  const unsigned short* V1H = (const unsigned short*)(wsb + OFF_V1H);
  const unsigned short* V1L = (const unsigned short*)(wsb + OFF_V1L);
  const unsigned short* V2H = (const unsigned short*)(wsb + OFF_V2H);
  const unsigned short* V2L = (const unsigned short*)(wsb + OFF_V2L);
  const unsigned short* MUH = (const unsigned short*)(wsb + OFF_MUH);
  const float* Gg  = (const float*)(wsb + OFF_G);
  const float* g0g = (const float*)(wsb + OFF_G0);

  // staging aliases into Bhi (dead until enc2 epilogue)
  float* obs_s = (float*)Bhi;            // [17][64] f32 = 4352 B
  float* ew1   = obs_s + NOBS * TS;      // [17][256] f32 = 17408 B (total 21760 < 32768)

  // ---- stage ----
  for (int t = tid; t < NOBS * TS; t += NT) {
    int s = t / NOBS, i = t - s * NOBS;
    obs_s[i * TS + s] = obs[(size_t)s0 * NOBS + t];
  }
  for (int t = tid; t < NOBS * HID; t += NT) ew1[t] = eW1[t];
  for (int t = tid; t < HID * NM; t += NT) Glds[t] = Gg[t];
  for (int t = tid; t < HID; t += NT) w3lds[t] = vW3[t];
  if (tid < 48) lslds[tid] = fminf(fmaxf(logstd[tid], -20.0f), 2.0f);
  __syncthreads();

  // ---- enc1 (fp32 VALU, lane=sample, wave owns 32 cols) -> Ahi/Alo (h) ----
  {
    float ob[NOBS];
#pragma unroll
    for (int i = 0; i < NOBS; ++i) ob[i] = obs_s[i * TS + lane];
    float accv[32];
#pragma unroll
    for (int c = 0; c < 32; ++c) accv[c] = eb1[c0 + c];
#pragma unroll
    for (int i = 0; i < NOBS; ++i) {
      const float* w = ew1 + i * HID + c0;
#pragma unroll
      for (int c = 0; c < 32; ++c) accv[c] = fmaf(ob[i], w[c], accv[c]);
    }
#pragma unroll
    for (int c = 0; c < 32; ++c) {
      float f = tanh_fast(accv[c]);
      unsigned short hi = f2bf(f);
      int id = aidx(lane, c0 + c);
      Ahi[id] = hi; Alo[id] = f2bf(f - bf2f(hi));
    }
  }
  __syncthreads();  // h ready; obs_s/ew1 dead

  // ---- enc2: feat = tanh(h @ W2 + b2), 3-pass split ----
  {
    f32x4 acc[4][2];
    gemm_tile<true, true>(Ahi, Alo, W2H, W2L, eb2, c0, l15, h, acc);
    epi_split(acc, Bhi, Blo, c0, l15, h);
  }
  __syncthreads();  // feat ready (Bhi/Blo)

  // ---- phase 4: routing score (all waves, chart=wid) + mu (waves 0-2) + val1 ----
  {
    float sc = g0g[wid];
#pragma unroll 8
    for (int kk = 0; kk < HID; kk += 2) {
      int id = aidx(lane, kk);  // even
      unsigned int uh = *(const unsigned int*)(Bhi + id);
      unsigned int ul = *(const unsigned int*)(Blo + id);
      float f0 = __uint_as_float(uh << 16) + __uint_as_float(ul << 16);
      float f1 = __uint_as_float(uh & 0xffff0000u) + __uint_as_float(ul & 0xffff0000u);
      sc = fmaf(f0, Glds[kk * NM + wid], sc);
      sc = fmaf(f1, Glds[(kk + 1) * NM + wid], sc);
    }
    sclds[wid * TS + lane] = sc;
  }
  if (wid < 3) {  // mu: 48 cols, A=feat (hi+lo), B=MUH (2-pass)
    f32x4 macc[4];
    float mb = mub[16 * wid + l15];
#pragma unroll
    for (int mt = 0; mt < 4; ++mt) macc[mt] = (f32x4){mb, mb, mb, mb};
#pragma unroll
    for (int kt = 0; kt < 8; ++kt) {
      int kb = kt * 32 + 8 * h;
      bf16x8 bh = *(const bf16x8*)(MUH + (16 * wid + l15) * HID + kb);
#pragma unroll
      for (int mt = 0; mt < 4; ++mt) {
        int s = 16 * mt + l15;
        bf16x8 ah = *(const bf16x8*)(Bhi + aidx(s, kb));
        bf16x8 al = *(const bf16x8*)(Blo + aidx(s, kb));
        macc[mt] = MFMA(ah, bh, macc[mt]);
        macc[mt] = MFMA(al, bh, macc[mt]);
      }
    }
#pragma unroll
    for (int mt = 0; mt < 4; ++mt)
#pragma unroll
      for (int r = 0; r < 4; ++r)
        mulds[(16 * wid + l15) * 65 + 16 * mt + 4 * h + r] = macc[mt][r];
  }
  {  // val1: v1 = tanh(feat @ vW1 + b1) -> Ahi/Alo (h dead)
    f32x4 acc[4][2];
    gemm_tile<true, true>(Bhi, Blo, V1H, V1L, vb1, c0, l15, h, acc);
    __syncthreads();  // scores/mu/val1 feat-reads done; safe to overwrite bufA? (bufA last read in enc2, barrier passed) -- this barrier orders mulds/sclds for final phase
    epi_split(acc, Ahi, Alo, c0, l15, h);
  }
  __syncthreads();  // v1 ready

  // ---- val2 + fused v reduction ----
  {
    f32x4 acc[4][2];
    gemm_tile<true, true>(Ahi, Alo, V2H, V2L, vb2, c0, l15, h, acc);
    float w30 = w3lds[c0 + l15], w31 = w3lds[c0 + 16 + l15];
#pragma unroll
    for (int mt = 0; mt < 4; ++mt)
#pragma unroll
      for (int r = 0; r < 4; ++r) {
        float t = tanh_fast(acc[mt][0][r]) * w30 + tanh_fast(acc[mt][1][r]) * w31;
#pragma unroll
        for (int m = 1; m <= 8; m <<= 1) t += __shfl_xor(t, m);
        if (l15 == 0) vpart[wid * TS + 16 * mt + 4 * h + r] = t;
      }
  }
  __syncthreads();

  // ---- final: argmin + flag + gather (wave 0) ----
  if (wid == 0) {
    int best = 0;
    float bs = sclds[lane], bs2 = 3.4e38f;
#pragma unroll
    for (int m = 1; m < NM; ++m) {
      float sm = sclds[m * TS + lane];
      if (sm < bs) { bs2 = bs; bs = sm; best = m; }
      else if (sm < bs2) bs2 = sm;
    }
    if (cnt && (bs2 - bs) < EPS_MARGIN) {
      int idx = atomicAdd(cnt, 1);
      if (idx < cap) flags[idx] = s0 + lane;
    }
    float v = vb3[0];
#pragma unroll
    for (int w = 0; w < NW; ++w) v += vpart[w * TS + lane];
    float* orow = out + (size_t)(s0 + lane) * NOUT;
#pragma unroll
    for (int a = 0; a < NACT; ++a) orow[a] = mulds[(best * NACT + a) * 65 + lane];
#pragma unroll
    for (int a = 0; a < NACT; ++a) orow[NACT + a] = lslds[best * NACT + a];
    orow[2 * NACT] = v;
  }
}

// ---------------- Pass B: fp64 recheck of flagged samples (verified, round 3) ----------------
extern "C" __global__ __launch_bounds__(256, 2)
void ppo_recheck(const float* __restrict__ obs,
                 const float* __restrict__ eW1, const float* __restrict__ eb1,
                 const float* __restrict__ eW2, const float* __restrict__ eb2,
                 const float* __restrict__ muW, const float* __restrict__ mub,
                 const float* __restrict__ logstd,
                 const float* __restrict__ cen, const float* __restrict__ smean,
                 const float* __restrict__ svar,
                 float* __restrict__ out,
                 const int* cnt, const int* flags, int cap)
{
  if (!cnt) return;
  __shared__ double hbuf[HID];
  __shared__ double fbuf[HID];
  __shared__ double d2buf[NM];
  __shared__ double obsd[NOBS];
  __shared__ int bestv;
  const int tid = threadIdx.x;
  const int n = min(cnt[0], cap);

  for (int i = blockIdx.x; i < n; i += gridDim.x) {
    const int s = flags[i];
    if (tid < NOBS) obsd[tid] = (double)obs[(size_t)s * NOBS + tid];
    __syncthreads();
    double a1 = (double)eb1[tid];
    for (int k = 0; k < NOBS; ++k) a1 = fma(obsd[k], (double)eW1[k * HID + tid], a1);
    hbuf[tid] = tanh(a1);
    __syncthreads();
    double a2 = (double)eb2[tid];
    for (int k = 0; k < HID; ++k) a2 = fma(hbuf[k], (double)eW2[k * HID + tid], a2);
    fbuf[tid] = tanh(a2);
    __syncthreads();
    {
      int g = tid >> 5, l = tid & 31;
      double dot = 0.0, zn = 0.0, cn = 0.0;
      for (int j = 0; j < HID / 32; ++j) {
        int k = l + j * 32;
        double zs = 1.0 / sqrt((double)svar[k] + 1e-6);
        double zw = (fbuf[k] - (double)smean[k]) * zs;
        double ck = (double)cen[g * HID + k];
        dot = fma(zw, ck, dot);
        zn  = fma(zw, zw, zn);
        cn  = fma(ck, ck, cn);
      }
      for (int m = 16; m >= 1; m >>= 1) {
        dot += __shfl_xor(dot, m, 32);
        zn  += __shfl_xor(zn,  m, 32);
        cn  += __shfl_xor(cn,  m, 32);
      }
      if (l == 0) d2buf[g] = zn - 2.0 * dot + cn;
    }
    __syncthreads();
    if (tid == 0) {
      int best = 0;
      double bs = d2buf[0];
      for (int m = 1; m < NM; ++m)
        if (d2buf[m] < bs) { bs = d2buf[m]; best = m; }
      bestv = best;
    }
    __syncthreads();
    const int best = bestv;
    if (tid < NACT) {
      float acc = mub[best * NACT + tid];
      for (int k = 0; k < HID; ++k)
        acc = fmaf((float)fbuf[k], muW[(best * HID + k) * NACT + tid], acc);
      out[(size_t)s * NOUT + tid] = acc;
    } else if (tid < 2 * NACT) {
      int a = tid - NACT;
      float ls = logstd[best * NACT + a];
      out[(size_t)s * NOUT + NACT + a] = fminf(fmaxf(ls, -20.0f), 2.0f);
    }
    __syncthreads();
  }
}

// ---------------- fallback (verified round-3 fp32 path, used only if ws too small) ----------------
extern "C" __global__ __launch_bounds__(NT, 4)
void ppo_fp32_fb(const float* __restrict__ obs,
                 const float* __restrict__ eW1, const float* __restrict__ eb1,
                 const float* __restrict__ eW2, const float* __restrict__ eb2,
                 const float* __restrict__ muW, const float* __restrict__ mub,
                 const float* __restrict__ logstd,
                 const float* __restrict__ vW1, const float* __restrict__ vb1,
                 const float* __restrict__ vW2, const float* __restrict__ vb2,
                 const float* __restrict__ vW3, const float* __restrict__ vb3,
                 const float* __restrict__ cen, const float* __restrict__ smean,
                 const float* __restrict__ svar,
                 float* __restrict__ out, int* cnt, int* flags, int cap)
{
  __shared__ float act[HID * TS];
  __shared__ float mubuf[NM * TS * NACT];
  __shared__ float scbuf[NM * TS];
  __shared__ float zsbuf[HID];
  const int tid  = threadIdx.x;
  const int lane = tid & 63;
  const int wid  = tid >> 6;
  const int c0   = wid * 32;
  const int s0   = blockIdx.x * TS;
  float* obs_s = mubuf;
  for (int idx = tid; idx < TS * NOBS; idx += NT) {
    int s = idx / NOBS, i = idx - s * NOBS;
    obs_s[i * TS + s] = obs[s0 * NOBS + idx];
  }
  if (tid < HID) zsbuf[tid] = (float)(1.0 / sqrt((double)svar[tid] + 1e-6));
  __syncthreads();
  {
    float acc[32];
#pragma unroll
    for (int c = 0; c < 32; ++c) acc[c] = eb1[c0 + c];
    float ob[NOBS];
#pragma unroll
    for (int i = 0; i < NOBS; ++i) ob[i] = obs_s[i * TS + lane];
#pragma unroll
    for (int i = 0; i < NOBS; ++i) {
      const float* w = &eW1[i * HID + c0];
#pragma unroll
      for (int c = 0; c < 32; ++c) acc[c] = fmaf(ob[i], w[c], acc[c]);
    }
#pragma unroll
    for (int c = 0; c < 32; ++c) act[(c0 + c) * TS + lane] = tanh_fast(acc[c]);
  }
  __syncthreads();
  {
    float acc[32];
#pragma unroll
    for (int c = 0; c < 32; ++c) acc[c] = eb2[c0 + c];
#pragma unroll 4
    for (int k = 0; k < HID; ++k) {
      float a = act[k * TS + lane];
      const float* w = &eW2[k * HID + c0];
#pragma unroll
      for (int c = 0; c < 32; ++c) acc[c] = fmaf(a, w[c], acc[c]);
    }
    __syncthreads();
#pragma unroll
    for (int c = 0; c < 32; ++c) act[(c0 + c) * TS + lane] = tanh_fast(acc[c]);
  }
  __syncthreads();
  {
    double dot = 0.0, zn = 0.0, cn = 0.0;
    float mu[NACT];
#pragma unroll
    for (int a = 0; a < NACT; ++a) mu[a] = mub[wid * NACT + a];
#pragma unroll 2
    for (int k = 0; k < HID; ++k) {
      float f = act[k * TS + lane];
      double zw = ((double)f - (double)smean[k]) * (double)zsbuf[k];
      double ck = (double)cen[wid * HID + k];
      dot = fma(zw, ck, dot); zn = fma(zw, zw, zn); cn = fma(ck, ck, cn);
      const float* w = &muW[(wid * HID + k) * NACT];
#pragma unroll
      for (int a = 0; a < NACT; ++a) mu[a] = fmaf(f, w[a], mu[a]);
    }
    scbuf[wid * TS + lane] = (float)(zn - 2.0 * dot + cn);
#pragma unroll
    for (int a = 0; a < NACT; ++a) mubuf[(wid * TS + lane) * NACT + a] = mu[a];
  }
  {
    float acc[32];
#pragma unroll
    for (int c = 0; c < 32; ++c) acc[c] = vb1[c0 + c];
#pragma unroll 4
    for (int k = 0; k < HID; ++k) {
      float f = act[k * TS + lane];
      const float* w = &vW1[k * HID + c0];
#pragma unroll
      for (int c = 0; c < 32; ++c) acc[c] = fmaf(f, w[c], acc[c]);
    }
    __syncthreads();
#pragma unroll
    for (int c = 0; c < 32; ++c) act[(c0 + c) * TS + lane] = tanh_fast(acc[c]);
  }
  __syncthreads();
  {
    float acc[32];
#pragma unroll
    for (int c = 0; c < 32; ++c) acc[c] = vb2[c0 + c];
#pragma unroll 4
    for (int k = 0; k < HID; ++k) {
      float f = act[k * TS + lane];
      const float* w = &vW2[k * HID + c0];
#pragma unroll
      for (int c = 0; c < 32; ++c) acc[c] = fmaf(f, w[c], acc[c]);
    }
    __syncthreads();
#pragma unroll
    for (int c = 0; c < 32; ++c) act[(c0 + c) * TS + lane] = tanh_fast(acc[c]);
  }
  __syncthreads();
  if (wid == 0) {
    int best = 0;
    float bs = scbuf[lane], bs2 = 3.4e38f;
#pragma unroll
    for (int m = 1; m < NM; ++m) {
      float sm = scbuf[m * TS + lane];
      if (sm < bs) { bs2 = bs; bs = sm; best = m; }
      else if (sm < bs2) bs2 = sm;
    }
    if (cnt && (bs2 - bs) < 1e-2f) {
      int idx = atomicAdd(cnt, 1);
      if (idx < cap) flags[idx] = s0 + lane;
    }
    float v = vb3[0];
#pragma unroll 4
    for (int k = 0; k < HID; ++k) v = fmaf(act[k * TS + lane], vW3[k], v);
    float* orow = &out[(size_t)(s0 + lane) * NOUT];
#pragma unroll
    for (int a = 0; a < NACT; ++a) orow[a] = mubuf[(best * TS + lane) * NACT + a];
#pragma unroll
    for (int a = 0; a < NACT; ++a) {
      float ls = logstd[best * NACT + a];
      orow[NACT + a] = fminf(fmaxf(ls, -20.0f), 2.0f);
    }
    orow[2 * NACT] = v;
  }
}

extern "C" void kernel_launch(void* const* d_in, const int* in_sizes, int n_in,
                              void* d_out, int out_size, void* d_ws, size_t ws_size,
                              hipStream_t stream) {
  const float* obs   = (const float*)d_in[0];
  const float* eW1   = (const float*)d_in[1];
  const float* eb1   = (const float*)d_in[2];
  const float* eW2   = (const float*)d_in[3];
  const float* eb2   = (const float*)d_in[4];
  const float* muW   = (const float*)d_in[5];
  const float* mub   = (const float*)d_in[6];
  const float* lstd  = (const float*)d_in[7];
  const float* vW1   = (const float*)d_in[8];
  const float* vb1   = (const float*)d_in[9];
  const float* vW2   = (const float*)d_in[10];
  const float* vb2   = (const float*)d_in[11];
  const float* vW3   = (const float*)d_in[12];
  const float* vb3   = (const float*)d_in[13];
  const float* cen   = (const float*)d_in[14];
  const float* smean = (const float*)d_in[15];
  const float* svar  = (const float*)d_in[16];
  float* out = (float*)d_out;
  unsigned char* wsb = (unsigned char*)d_ws;

  if (ws_size >= (size_t)WS_NEED) {
    int* cnt = (int*)wsb;
    int* flags = (int*)(wsb + OFF_FLAGS);
    hipLaunchKernelGGL(ppo_zero, dim3(1), dim3(64), 0, stream, cnt);
    hipLaunchKernelGGL(ppo_prep, dim3(256), dim3(256), 0, stream,
                       eW2, vW1, vW2, muW, cen, svar, wsb);
    hipLaunchKernelGGL(ppo_prep_g0, dim3(1), dim3(NT), 0, stream, cen, smean, svar, wsb);
    hipLaunchKernelGGL(ppo_mfma, dim3(B_TOT / TS), dim3(NT), 0, stream,
                       obs, eW1, eb1, eb2, mub, lstd, vb1, vb2, vW3, vb3,
                       (const unsigned char*)wsb, out, cnt, flags, CAPF);
    hipLaunchKernelGGL(ppo_recheck, dim3(512), dim3(256), 0, stream,
                       obs, eW1, eb1, eW2, eb2, muW, mub, lstd,
                       cen, smean, svar, out, cnt, flags, CAPF);
  } else {
    int* cnt = nullptr; int* flags = nullptr; int cap = 0;
    if (ws_size >= 1024) {
      cnt = (int*)wsb;
      flags = cnt + 16;
      size_t c = (ws_size - 64) / 4;
      cap = (int)(c < (size_t)CAPF ? c : (size_t)CAPF);
    }
    hipLaunchKernelGGL(ppo_zero, dim3(1), dim3(64), 0, stream, cnt);
    hipLaunchKernelGGL(ppo_fp32_fb, dim3(B_TOT / TS), dim3(NT), 0, stream,
                       obs, eW1, eb1, eW2, eb2, muW, mub, lstd,
                       vW1, vb1, vW2, vb2, vW3, vb3, cen, smean, svar, out,
                       cnt, flags, cap);
    hipLaunchKernelGGL(ppo_recheck, dim3(512), dim3(256), 0, stream,
                       obs, eW1, eb1, eW2, eb2, muW, mub, lstd,
                       cen, smean, svar, out, cnt, flags, cap);
  }
}

// Round 6
// 219.862 us; speedup vs baseline: 15.4227x; 1.9398x over previous
//
#include <hip/hip_runtime.h>
#include <math.h>

typedef __attribute__((ext_vector_type(8))) short bf16x8;
typedef __attribute__((ext_vector_type(4))) float f32x4;

#define B_TOT 131072
#define NOBS 17
#define NACT 6
#define NM 8
#define HID 256
#define TS 64
#define NT 512
#define NW 8
#define NOUT 13
#define EPS_MARGIN 0.20f   // 10-sigma of score-diff error (bf16 feat+G + single-pass enc2)
#define CAPF 65536

// LDS row strides (elements)
#define AST 264
#define OST 40
#define MUST 52
#define SCST 12

// ---- workspace layout (bytes) ----
#define OFF_FLAGS 64
#define OFF_W1H  (OFF_FLAGS + 4*CAPF)       /* [256][32] bf16 hi */
#define OFF_W1L  (OFF_W1H + 256*32*2)
#define OFF_W2T  (OFF_W1L + 256*32*2)       /* [256][256] bf16, transposed */
#define OFF_V1T  (OFF_W2T + 256*256*2)
#define OFF_V2T  (OFF_V1T + 256*256*2)
#define OFF_HDT  (OFF_V2T + 256*256*2)      /* [64][256]: 48 mu cols | 8 G cols | 8 pad */
#define OFF_G0   (OFF_HDT + 64*256*2)
#define WS_NEED  (OFF_G0 + 64)

__device__ __forceinline__ unsigned short f2bf(float f) {  // RNE
  unsigned int u = __float_as_uint(f);
  u = (u + 0x7fffu + ((u >> 16) & 1u)) >> 16;
  return (unsigned short)u;
}
__device__ __forceinline__ float bf2f(unsigned short h) {
  return __uint_as_float(((unsigned int)h) << 16);
}
__device__ __forceinline__ float tanh_fast2(float x) {
  float e = __expf(2.0f * x);
  float r = __builtin_amdgcn_rcpf(e + 1.0f);
  return 1.0f - 2.0f * r;
}
__device__ __forceinline__ unsigned int pk2(float a, float b) {  // lo16=bf(a), hi16=bf(b)
  unsigned int r;
  asm("v_cvt_pk_bf16_f32 %0, %1, %2" : "=v"(r) : "v"(a), "v"(b));
  return r;
}
__device__ __forceinline__ f32x4 MFMA(bf16x8 a, bf16x8 b, f32x4 c) {
  return __builtin_amdgcn_mfma_f32_16x16x32_bf16(a, b, c, 0, 0, 0);
}

extern "C" __global__ void ppo_zero(int* cnt) {
  if (cnt && threadIdx.x == 0) cnt[0] = 0;
}

// ---------------- prep: transpose weights to bf16, build head matrix ----------------
extern "C" __global__ __launch_bounds__(256)
void ppo_prep(const float* __restrict__ eW1, const float* __restrict__ eW2,
              const float* __restrict__ vW1, const float* __restrict__ vW2,
              const float* __restrict__ muW, const float* __restrict__ cen,
              const float* __restrict__ svar, unsigned char* wsb)
{
  int t = blockIdx.x * 256 + threadIdx.x;
  if (t < 65536) {                       // W2T[c][k] = eW2[k][c]
    int c = t >> 8, k = t & 255;
    ((unsigned short*)(wsb + OFF_W2T))[c * 256 + k] = f2bf(eW2[k * 256 + c]);
  } else if (t < 131072) {
    int u = t - 65536; int c = u >> 8, k = u & 255;
    ((unsigned short*)(wsb + OFF_V1T))[c * 256 + k] = f2bf(vW1[k * 256 + c]);
  } else if (t < 196608) {
    int u = t - 131072; int c = u >> 8, k = u & 255;
    ((unsigned short*)(wsb + OFF_V2T))[c * 256 + k] = f2bf(vW2[k * 256 + c]);
  } else if (t < 212992) {               // HDT: mu cols 0-47, G cols 48-55, pad 56-63
    int u = t - 196608; int c = u >> 8, k = u & 255;
    float v = 0.f;
    if (c < 48) { int m = c / 6, a = c - 6 * m; v = muW[(m * 256 + k) * 6 + a]; }
    else if (c < 56) {
      int m = c - 48;
      double s = 1.0 / sqrt((double)svar[k] + 1e-6);
      v = (float)(-2.0 * s * (double)cen[m * 256 + k]);
    }
    ((unsigned short*)(wsb + OFF_HDT))[c * 256 + k] = f2bf(v);
  } else if (t < 221184) {               // W1T hi/lo, K padded 17->32
    int u = t - 212992; int c = u >> 5, k = u & 31;
    float v = (k < NOBS) ? eW1[k * 256 + c] : 0.f;
    unsigned short hi = f2bf(v);
    ((unsigned short*)(wsb + OFF_W1H))[c * 32 + k] = hi;
    ((unsigned short*)(wsb + OFF_W1L))[c * 32 + k] = f2bf(v - bf2f(hi));
  }
}

extern "C" __global__ __launch_bounds__(NT)
void ppo_prep_g0(const float* __restrict__ cen, const float* __restrict__ smean,
                 const float* __restrict__ svar, unsigned char* wsb)
{
  int m = threadIdx.x >> 6, lane = threadIdx.x & 63;
  double acc = 0.0;
  for (int k = lane; k < HID; k += 64) {
    double s = 1.0 / sqrt((double)svar[k] + 1e-6);
    double c = (double)cen[m * HID + k];
    acc += c * (2.0 * (double)smean[k] * s + c);
  }
#pragma unroll
  for (int w = 32; w >= 1; w >>= 1) acc += __shfl_xor(acc, w);
  if (lane == 0) ((float*)(wsb + OFF_G0))[m] = (float)acc;
}

// ---- K=256 single-pass gemm: A = weights (global, transposed), B = activations (LDS)
template<int CT>
__device__ __forceinline__ void gemm256(const unsigned short* __restrict__ WT,
                                        const unsigned short* act,
                                        int cb, int l15, int h, f32x4 acc[CT][4])
{
#pragma unroll
  for (int kt = 0; kt < 8; ++kt) {
    int kk = kt * 32 + 8 * h;
    bf16x8 a[CT], b[4];
#pragma unroll
    for (int ct = 0; ct < CT; ++ct)
      a[ct] = *(const bf16x8*)(WT + (cb + 16 * ct + l15) * 256 + kk);
#pragma unroll
    for (int nt = 0; nt < 4; ++nt)
      b[nt] = *(const bf16x8*)(act + (16 * nt + l15) * AST + kk);
#pragma unroll
    for (int ct = 0; ct < CT; ++ct)
#pragma unroll
      for (int nt = 0; nt < 4; ++nt)
        acc[ct][nt] = MFMA(a[ct], b[nt], acc[ct][nt]);
  }
}

// epilogue: tanh -> bf16 -> one b64 write per tile
__device__ __forceinline__ void epi_tanh_store(f32x4 acc[2][4], unsigned short* dst,
                                               int cb, int l15, int h)
{
#pragma unroll
  for (int ct = 0; ct < 2; ++ct)
#pragma unroll
    for (int nt = 0; nt < 4; ++nt) {
      float t0 = tanh_fast2(acc[ct][nt][0]);
      float t1 = tanh_fast2(acc[ct][nt][1]);
      float t2 = tanh_fast2(acc[ct][nt][2]);
      float t3 = tanh_fast2(acc[ct][nt][3]);
      uint2 u; u.x = pk2(t0, t1); u.y = pk2(t2, t3);
      *(uint2*)(dst + (16 * nt + l15) * AST + cb + 16 * ct + 4 * h) = u;
    }
}

// ---------------- main fused kernel ----------------
extern "C" __global__ __launch_bounds__(NT, 4)
void ppo_mfma(const float* __restrict__ obs,
              const float* __restrict__ eb1, const float* __restrict__ eb2,
              const float* __restrict__ mub, const float* __restrict__ logstd,
              const float* __restrict__ vb1, const float* __restrict__ vb2,
              const float* __restrict__ vW3, const float* __restrict__ vb3,
              const unsigned char* __restrict__ wsb,
              float* __restrict__ out, int* cnt, int* flags, int cap)
{
  __shared__ unsigned short Hb[TS * AST];   // 33792 B: h, then v1
  __shared__ unsigned short Fb[TS * AST];   // 33792 B: feat (front aliased by obs staging)
  __shared__ unsigned short MU[TS * MUST];  // 6656 B
  __shared__ float SC[TS * SCST];           // 3072 B
  __shared__ float VP[NW * TS];             // 2048 B
  __shared__ float LS[48];                  // total 79552 B -> 2 blocks/CU

  const int tid = threadIdx.x, lane = tid & 63, wid = tid >> 6;
  const int l15 = lane & 15, h = lane >> 4;
  const int cb = wid * 32;
  const int s0 = blockIdx.x * TS;

  const unsigned short* W1H = (const unsigned short*)(wsb + OFF_W1H);
  const unsigned short* W1L = (const unsigned short*)(wsb + OFF_W1L);
  const unsigned short* W2T = (const unsigned short*)(wsb + OFF_W2T);
  const unsigned short* V1T = (const unsigned short*)(wsb + OFF_V1T);
  const unsigned short* V2T = (const unsigned short*)(wsb + OFF_V2T);
  const unsigned short* HDT = (const unsigned short*)(wsb + OFF_HDT);
  const float* g0g = (const float*)(wsb + OFF_G0);

  unsigned short* OBH = Fb;                 // [64][40] obs hi (alias; dead before Fb written)
  unsigned short* OBL = Fb + TS * OST;      // [64][40] obs lo

  // ---- stage: obs split hi/lo, zero K-pad, logstd clamp
  for (int t = tid; t < TS * NOBS; t += NT) {
    int s = t / NOBS, k = t - NOBS * s;
    float v = obs[(size_t)s0 * NOBS + t];
    unsigned short hi = f2bf(v);
    OBH[s * OST + k] = hi;
    OBL[s * OST + k] = f2bf(v - bf2f(hi));
  }
  for (int t = tid; t < TS * (32 - NOBS); t += NT) {
    int s = t / (32 - NOBS), k = NOBS + t - (32 - NOBS) * s;
    OBH[s * OST + k] = 0; OBL[s * OST + k] = 0;
  }
  if (tid < 48) LS[tid] = fminf(fmaxf(logstd[tid], -20.f), 2.f);
  __syncthreads();

  // ---- enc1: h = tanh(obs @ W1 + b1), K=32, 3-pass split
  {
    f32x4 acc[2][4];
    f32x4 b0 = *(const f32x4*)(eb1 + cb + 4 * h);
    f32x4 b1 = *(const f32x4*)(eb1 + cb + 16 + 4 * h);
#pragma unroll
    for (int nt = 0; nt < 4; ++nt) { acc[0][nt] = b0; acc[1][nt] = b1; }
    bf16x8 aH[2], aL[2], bH[4], bL[4];
#pragma unroll
    for (int ct = 0; ct < 2; ++ct) {
      aH[ct] = *(const bf16x8*)(W1H + (cb + 16 * ct + l15) * 32 + 8 * h);
      aL[ct] = *(const bf16x8*)(W1L + (cb + 16 * ct + l15) * 32 + 8 * h);
    }
#pragma unroll
    for (int nt = 0; nt < 4; ++nt) {
      bH[nt] = *(const bf16x8*)(OBH + (16 * nt + l15) * OST + 8 * h);
      bL[nt] = *(const bf16x8*)(OBL + (16 * nt + l15) * OST + 8 * h);
    }
#pragma unroll
    for (int ct = 0; ct < 2; ++ct)
#pragma unroll
      for (int nt = 0; nt < 4; ++nt) {
        acc[ct][nt] = MFMA(aH[ct], bH[nt], acc[ct][nt]);
        acc[ct][nt] = MFMA(aL[ct], bH[nt], acc[ct][nt]);
        acc[ct][nt] = MFMA(aH[ct], bL[nt], acc[ct][nt]);
      }
    epi_tanh_store(acc, Hb, cb, l15, h);
  }
  __syncthreads();  // h ready; obs dead

  // ---- enc2: feat = tanh(h @ W2 + b2)
  {
    f32x4 acc[2][4];
    f32x4 b0 = *(const f32x4*)(eb2 + cb + 4 * h);
    f32x4 b1 = *(const f32x4*)(eb2 + cb + 16 + 4 * h);
#pragma unroll
    for (int nt = 0; nt < 4; ++nt) { acc[0][nt] = b0; acc[1][nt] = b1; }
    gemm256<2>(W2T, Hb, cb, l15, h, acc);
    epi_tanh_store(acc, Fb, cb, l15, h);
  }
  __syncthreads();  // feat ready

  // ---- phase 4: val1 (all waves) + heads mu/score (waves 0-3); all read Fb only
  {
    f32x4 acc[2][4];
    f32x4 b0 = *(const f32x4*)(vb1 + cb + 4 * h);
    f32x4 b1 = *(const f32x4*)(vb1 + cb + 16 + 4 * h);
#pragma unroll
    for (int nt = 0; nt < 4; ++nt) { acc[0][nt] = b0; acc[1][nt] = b1; }
    gemm256<2>(V1T, Fb, cb, l15, h, acc);
    epi_tanh_store(acc, Hb, cb, l15, h);  // v1 overwrites h (dead after enc2 + barrier)
  }
  if (wid < 4) {
    f32x4 hacc[1][4];
    f32x4 hb;
    if (wid < 3)      hb = *(const f32x4*)(mub + 16 * wid + 4 * h);
    else if (h < 2)   hb = *(const f32x4*)(g0g + 4 * h);
    else              hb = (f32x4){0.f, 0.f, 0.f, 0.f};
#pragma unroll
    for (int nt = 0; nt < 4; ++nt) hacc[0][nt] = hb;
    gemm256<1>(HDT, Fb, 16 * wid, l15, h, hacc);
    if (wid < 3) {
#pragma unroll
      for (int nt = 0; nt < 4; ++nt) {
        uint2 u;
        u.x = pk2(hacc[0][nt][0], hacc[0][nt][1]);
        u.y = pk2(hacc[0][nt][2], hacc[0][nt][3]);
        *(uint2*)(MU + (16 * nt + l15) * MUST + 16 * wid + 4 * h) = u;
      }
    } else if (h < 2) {
#pragma unroll
      for (int nt = 0; nt < 4; ++nt)
        *(f32x4*)(SC + (16 * nt + l15) * SCST + 4 * h) = hacc[0][nt];
    }
  }
  __syncthreads();  // v1 / mu / scores ready

  // ---- val2 + fused v = v2 @ W3 reduction
  {
    f32x4 acc[2][4];
    f32x4 b0 = *(const f32x4*)(vb2 + cb + 4 * h);
    f32x4 b1 = *(const f32x4*)(vb2 + cb + 16 + 4 * h);
#pragma unroll
    for (int nt = 0; nt < 4; ++nt) { acc[0][nt] = b0; acc[1][nt] = b1; }
    gemm256<2>(V2T, Hb, cb, l15, h, acc);
    f32x4 w30 = *(const f32x4*)(vW3 + cb + 4 * h);
    f32x4 w31 = *(const f32x4*)(vW3 + cb + 16 + 4 * h);
#pragma unroll
    for (int nt = 0; nt < 4; ++nt) {
      float v = 0.f;
#pragma unroll
      for (int r = 0; r < 4; ++r) {
        v = fmaf(tanh_fast2(acc[0][nt][r]), w30[r], v);
        v = fmaf(tanh_fast2(acc[1][nt][r]), w31[r], v);
      }
      v += __shfl_xor(v, 16);
      v += __shfl_xor(v, 32);
      if (h == 0) VP[wid * TS + 16 * nt + l15] = v;
    }
  }
  __syncthreads();

  // ---- final: argmin + near-tie flag + gather (wave 0; lane = sample)
  if (wid == 0) {
    int s = lane;
    int best = 0;
    float bs = SC[s * SCST], bs2 = 3.4e38f;
#pragma unroll
    for (int m = 1; m < NM; ++m) {
      float sm = SC[s * SCST + m];
      if (sm < bs) { bs2 = bs; bs = sm; best = m; }  // strict <: first min on tie
      else if (sm < bs2) bs2 = sm;
    }
    if (cnt && (bs2 - bs) < EPS_MARGIN) {
      int idx = atomicAdd(cnt, 1);
      if (idx < cap) flags[idx] = s0 + s;
    }
    float v = vb3[0];
#pragma unroll
    for (int w = 0; w < NW; ++w) v += VP[w * TS + s];
    float* orow = out + (size_t)(s0 + s) * NOUT;
#pragma unroll
    for (int a = 0; a < NACT; ++a) orow[a] = bf2f(MU[s * MUST + best * NACT + a]);
#pragma unroll
    for (int a = 0; a < NACT; ++a) orow[NACT + a] = LS[best * NACT + a];
    orow[2 * NACT] = v;
  }
}

// ---------------- Pass B: fp64 recheck of flagged samples (verified, round 3) ----------------
extern "C" __global__ __launch_bounds__(256, 2)
void ppo_recheck(const float* __restrict__ obs,
                 const float* __restrict__ eW1, const float* __restrict__ eb1,
                 const float* __restrict__ eW2, const float* __restrict__ eb2,
                 const float* __restrict__ muW, const float* __restrict__ mub,
                 const float* __restrict__ logstd,
                 const float* __restrict__ cen, const float* __restrict__ smean,
                 const float* __restrict__ svar,
                 float* __restrict__ out,
                 const int* cnt, const int* flags, int cap)
{
  if (!cnt) return;
  __shared__ double hbuf[HID];
  __shared__ double fbuf[HID];
  __shared__ double d2buf[NM];
  __shared__ double obsd[NOBS];
  __shared__ int bestv;
  const int tid = threadIdx.x;
  const int n = min(cnt[0], cap);

  for (int i = blockIdx.x; i < n; i += gridDim.x) {
    const int s = flags[i];
    if (tid < NOBS) obsd[tid] = (double)obs[(size_t)s * NOBS + tid];
    __syncthreads();
    double a1 = (double)eb1[tid];
    for (int k = 0; k < NOBS; ++k) a1 = fma(obsd[k], (double)eW1[k * HID + tid], a1);
    hbuf[tid] = tanh(a1);
    __syncthreads();
    double a2 = (double)eb2[tid];
    for (int k = 0; k < HID; ++k) a2 = fma(hbuf[k], (double)eW2[k * HID + tid], a2);
    fbuf[tid] = tanh(a2);
    __syncthreads();
    {
      int g = tid >> 5, l = tid & 31;
      double dot = 0.0, zn = 0.0, cn = 0.0;
      for (int j = 0; j < HID / 32; ++j) {
        int k = l + j * 32;
        double zs = 1.0 / sqrt((double)svar[k] + 1e-6);
        double zw = (fbuf[k] - (double)smean[k]) * zs;
        double ck = (double)cen[g * HID + k];
        dot = fma(zw, ck, dot);
        zn  = fma(zw, zw, zn);
        cn  = fma(ck, ck, cn);
      }
      for (int m = 16; m >= 1; m >>= 1) {
        dot += __shfl_xor(dot, m, 32);
        zn  += __shfl_xor(zn,  m, 32);
        cn  += __shfl_xor(cn,  m, 32);
      }
      if (l == 0) d2buf[g] = zn - 2.0 * dot + cn;
    }
    __syncthreads();
    if (tid == 0) {
      int best = 0;
      double bs = d2buf[0];
      for (int m = 1; m < NM; ++m)
        if (d2buf[m] < bs) { bs = d2buf[m]; best = m; }
      bestv = best;
    }
    __syncthreads();
    const int best = bestv;
    if (tid < NACT) {
      float acc = mub[best * NACT + tid];
      for (int k = 0; k < HID; ++k)
        acc = fmaf((float)fbuf[k], muW[(best * HID + k) * NACT + tid], acc);
      out[(size_t)s * NOUT + tid] = acc;
    } else if (tid < 2 * NACT) {
      int a = tid - NACT;
      float ls = logstd[best * NACT + a];
      out[(size_t)s * NOUT + NACT + a] = fminf(fmaxf(ls, -20.0f), 2.0f);
    }
    __syncthreads();
  }
}

// ---------------- fallback (verified round-3 fp32 path; unused when ws is big) ----------------
extern "C" __global__ __launch_bounds__(NT, 4)
void ppo_fp32_fb(const float* __restrict__ obs,
                 const float* __restrict__ eW1, const float* __restrict__ eb1,
                 const float* __restrict__ eW2, const float* __restrict__ eb2,
                 const float* __restrict__ muW, const float* __restrict__ mub,
                 const float* __restrict__ logstd,
                 const float* __restrict__ vW1, const float* __restrict__ vb1,
                 const float* __restrict__ vW2, const float* __restrict__ vb2,
                 const float* __restrict__ vW3, const float* __restrict__ vb3,
                 const float* __restrict__ cen, const float* __restrict__ smean,
                 const float* __restrict__ svar,
                 float* __restrict__ out, int* cnt, int* flags, int cap)
{
  __shared__ float act[HID * TS];
  __shared__ float mubuf[NM * TS * NACT];
  __shared__ float scbuf[NM * TS];
  __shared__ float zsbuf[HID];
  const int tid  = threadIdx.x;
  const int lane = tid & 63;
  const int wid  = tid >> 6;
  const int c0   = wid * 32;
  const int s0   = blockIdx.x * TS;
  float* obs_s = mubuf;
  for (int idx = tid; idx < TS * NOBS; idx += NT) {
    int s = idx / NOBS, i = idx - s * NOBS;
    obs_s[i * TS + s] = obs[s0 * NOBS + idx];
  }
  if (tid < HID) zsbuf[tid] = (float)(1.0 / sqrt((double)svar[tid] + 1e-6));
  __syncthreads();
  {
    float acc[32];
#pragma unroll
    for (int c = 0; c < 32; ++c) acc[c] = eb1[c0 + c];
    float ob[NOBS];
#pragma unroll
    for (int i = 0; i < NOBS; ++i) ob[i] = obs_s[i * TS + lane];
#pragma unroll
    for (int i = 0; i < NOBS; ++i) {
      const float* w = &eW1[i * HID + c0];
#pragma unroll
      for (int c = 0; c < 32; ++c) acc[c] = fmaf(ob[i], w[c], acc[c]);
    }
#pragma unroll
    for (int c = 0; c < 32; ++c) act[(c0 + c) * TS + lane] = tanh_fast2(acc[c]);
  }
  __syncthreads();
  {
    float acc[32];
#pragma unroll
    for (int c = 0; c < 32; ++c) acc[c] = eb2[c0 + c];
#pragma unroll 4
    for (int k = 0; k < HID; ++k) {
      float a = act[k * TS + lane];
      const float* w = &eW2[k * HID + c0];
#pragma unroll
      for (int c = 0; c < 32; ++c) acc[c] = fmaf(a, w[c], acc[c]);
    }
    __syncthreads();
#pragma unroll
    for (int c = 0; c < 32; ++c) act[(c0 + c) * TS + lane] = tanh_fast2(acc[c]);
  }
  __syncthreads();
  {
    double dot = 0.0, zn = 0.0, cn = 0.0;
    float mu[NACT];
#pragma unroll
    for (int a = 0; a < NACT; ++a) mu[a] = mub[wid * NACT + a];
#pragma unroll 2
    for (int k = 0; k < HID; ++k) {
      float f = act[k * TS + lane];
      double zw = ((double)f - (double)smean[k]) * (double)zsbuf[k];
      double ck = (double)cen[wid * HID + k];
      dot = fma(zw, ck, dot); zn = fma(zw, zw, zn); cn = fma(ck, ck, cn);
      const float* w = &muW[(wid * HID + k) * NACT];
#pragma unroll
      for (int a = 0; a < NACT; ++a) mu[a] = fmaf(f, w[a], mu[a]);
    }
    scbuf[wid * TS + lane] = (float)(zn - 2.0 * dot + cn);
#pragma unroll
    for (int a = 0; a < NACT; ++a) mubuf[(wid * TS + lane) * NACT + a] = mu[a];
  }
  {
    float acc[32];
#pragma unroll
    for (int c = 0; c < 32; ++c) acc[c] = vb1[c0 + c];
#pragma unroll 4
    for (int k = 0; k < HID; ++k) {
      float f = act[k * TS + lane];
      const float* w = &vW1[k * HID + c0];
#pragma unroll
      for (int c = 0; c < 32; ++c) acc[c] = fmaf(f, w[c], acc[c]);
    }
    __syncthreads();
#pragma unroll
    for (int c = 0; c < 32; ++c) act[(c0 + c) * TS + lane] = tanh_fast2(acc[c]);
  }
  __syncthreads();
  {
    float acc[32];
#pragma unroll
    for (int c = 0; c < 32; ++c) acc[c] = vb2[c0 + c];
#pragma unroll 4
    for (int k = 0; k < HID; ++k) {
      float f = act[k * TS + lane];
      const float* w = &vW2[k * HID + c0];
#pragma unroll
      for (int c = 0; c < 32; ++c) acc[c] = fmaf(f, w[c], acc[c]);
    }
    __syncthreads();
#pragma unroll
    for (int c = 0; c < 32; ++c) act[(c0 + c) * TS + lane] = tanh_fast2(acc[c]);
  }
  __syncthreads();
  if (wid == 0) {
    int best = 0;
    float bs = scbuf[lane], bs2 = 3.4e38f;
#pragma unroll
    for (int m = 1; m < NM; ++m) {
      float sm = scbuf[m * TS + lane];
      if (sm < bs) { bs2 = bs; bs = sm; best = m; }
      else if (sm < bs2) bs2 = sm;
    }
    if (cnt && (bs2 - bs) < 1e-2f) {
      int idx = atomicAdd(cnt, 1);
      if (idx < cap) flags[idx] = s0 + lane;
    }
    float v = vb3[0];
#pragma unroll 4
    for (int k = 0; k < HID; ++k) v = fmaf(act[k * TS + lane], vW3[k], v);
    float* orow = &out[(size_t)(s0 + lane) * NOUT];
#pragma unroll
    for (int a = 0; a < NACT; ++a) orow[a] = mubuf[(best * TS + lane) * NACT + a];
#pragma unroll
    for (int a = 0; a < NACT; ++a) {
      float ls = logstd[best * NACT + a];
      orow[NACT + a] = fminf(fmaxf(ls, -20.0f), 2.0f);
    }
    orow[2 * NACT] = v;
  }
}

extern "C" void kernel_launch(void* const* d_in, const int* in_sizes, int n_in,
                              void* d_out, int out_size, void* d_ws, size_t ws_size,
                              hipStream_t stream) {
  const float* obs   = (const float*)d_in[0];
  const float* eW1   = (const float*)d_in[1];
  const float* eb1   = (const float*)d_in[2];
  const float* eW2   = (const float*)d_in[3];
  const float* eb2   = (const float*)d_in[4];
  const float* muW   = (const float*)d_in[5];
  const float* mub   = (const float*)d_in[6];
  const float* lstd  = (const float*)d_in[7];
  const float* vW1   = (const float*)d_in[8];
  const float* vb1   = (const float*)d_in[9];
  const float* vW2   = (const float*)d_in[10];
  const float* vb2   = (const float*)d_in[11];
  const float* vW3   = (const float*)d_in[12];
  const float* vb3   = (const float*)d_in[13];
  const float* cen   = (const float*)d_in[14];
  const float* smean = (const float*)d_in[15];
  const float* svar  = (const float*)d_in[16];
  float* out = (float*)d_out;
  unsigned char* wsb = (unsigned char*)d_ws;

  if (ws_size >= (size_t)WS_NEED) {
    int* cnt = (int*)wsb;
    int* flags = (int*)(wsb + OFF_FLAGS);
    hipLaunchKernelGGL(ppo_zero, dim3(1), dim3(64), 0, stream, cnt);
    hipLaunchKernelGGL(ppo_prep, dim3(864), dim3(256), 0, stream,
                       eW1, eW2, vW1, vW2, muW, cen, svar, wsb);
    hipLaunchKernelGGL(ppo_prep_g0, dim3(1), dim3(NT), 0, stream, cen, smean, svar, wsb);
    hipLaunchKernelGGL(ppo_mfma, dim3(B_TOT / TS), dim3(NT), 0, stream,
                       obs, eb1, eb2, mub, lstd, vb1, vb2, vW3, vb3,
                       (const unsigned char*)wsb, out, cnt, flags, CAPF);
    hipLaunchKernelGGL(ppo_recheck, dim3(2048), dim3(256), 0, stream,
                       obs, eW1, eb1, eW2, eb2, muW, mub, lstd,
                       cen, smean, svar, out, cnt, flags, CAPF);
  } else {
    int* cnt = nullptr; int* flags = nullptr; int cap = 0;
    if (ws_size >= 1024) {
      cnt = (int*)wsb;
      flags = cnt + 16;
      size_t c = (ws_size - 64) / 4;
      cap = (int)(c < (size_t)CAPF ? c : (size_t)CAPF);
    }
    hipLaunchKernelGGL(ppo_zero, dim3(1), dim3(64), 0, stream, cnt);
    hipLaunchKernelGGL(ppo_fp32_fb, dim3(B_TOT / TS), dim3(NT), 0, stream,
                       obs, eW1, eb1, eW2, eb2, muW, mub, lstd,
                       vW1, vb1, vW2, vb2, vW3, vb3, cen, smean, svar, out,
                       cnt, flags, cap);
    hipLaunchKernelGGL(ppo_recheck, dim3(2048), dim3(256), 0, stream,
                       obs, eW1, eb1, eW2, eb2, muW, mub, lstd,
                       cen, smean, svar, out, cnt, flags, cap);
  }
}